// Round 1
// baseline (344.462 us; speedup 1.0000x reference)
//
#include <hip/hip_runtime.h>
#include <hip/hip_bf16.h>

typedef __attribute__((ext_vector_type(4))) float f32x4;
typedef __attribute__((ext_vector_type(8))) __bf16 bf16x8;

#define B_    2
#define S_    2048
#define HID_  2048
#define H_    16
#define HD_   128
#define M_    (B_*S_)    // 4096
#define NQKV_ 6144
#define LN10000_OVER16 0.5756462732485114f

#define GLD16(gp, lp) \
  __builtin_amdgcn_global_load_lds((const __attribute__((address_space(1))) void*)(gp), \
                                   (__attribute__((address_space(3))) void*)(lp), 16, 0, 0)

// ---------------- f32 -> bf16 flat convert (vectorized) ----------------
__global__ __launch_bounds__(256) void k_cvt_bf16(const float* __restrict__ x,
                                                  __hip_bfloat16* __restrict__ y, int n4) {
  int i = blockIdx.x * 256 + threadIdx.x;
  if (i >= n4) return;
  float4 v = ((const float4*)x)[i];
  union { __hip_bfloat16 h[4]; uint2 u; } o;
  o.h[0] = __float2bfloat16(v.x); o.h[1] = __float2bfloat16(v.y);
  o.h[2] = __float2bfloat16(v.z); o.h[3] = __float2bfloat16(v.w);
  *(uint2*)(y + 4*(size_t)i) = o.u;
}

// ---------------- W [K][N] f32 -> Wt [N][K] bf16 ----------------
__global__ __launch_bounds__(256) void k_transpose_w(const float* __restrict__ W,
                                                     __hip_bfloat16* __restrict__ Wt,
                                                     int K, int N) {
  __shared__ float tile[32][33];
  int k0 = blockIdx.x * 32, n0 = blockIdx.y * 32;
  int tx = threadIdx.x, ty = threadIdx.y;  // 32 x 8
  #pragma unroll
  for (int i = 0; i < 4; ++i)
    tile[ty + i*8][tx] = W[(size_t)(k0 + ty + i*8)*N + n0 + tx];
  __syncthreads();
  #pragma unroll
  for (int i = 0; i < 4; ++i)
    Wt[(size_t)(n0 + ty + i*8)*K + k0 + tx] = __float2bfloat16(tile[tx][ty + i*8]);
}

// ---------------- V [bh][S][HD] -> VT [bh][HD][S] (bf16) ----------------
__global__ __launch_bounds__(256) void k_transpose_v(const __hip_bfloat16* __restrict__ V,
                                                     __hip_bfloat16* __restrict__ VT) {
  __shared__ __hip_bfloat16 tile[32][33];
  int s0 = blockIdx.x * 32, d0 = blockIdx.y * 32, bh = blockIdx.z;
  int tx = threadIdx.x, ty = threadIdx.y;  // 32 x 8
  size_t base = (size_t)bh * S_ * HD_;
  #pragma unroll
  for (int i = 0; i < 4; ++i)
    tile[ty + i*8][tx] = V[base + (size_t)(s0 + ty + i*8)*HD_ + d0 + tx];
  __syncthreads();
  #pragma unroll
  for (int i = 0; i < 4; ++i)
    VT[base + (size_t)(d0 + ty + i*8)*S_ + s0 + tx] = tile[tx][ty + i*8];
}

// ---------------- GEMM: C[M,N] = A[M,K](bf16,rowmaj) @ Bt[N,K](bf16,rowmaj)^T ----------------
// 128x128 tile, BK=32, 4 waves (2x2), 4x4 16x16x32 fragments per wave.
// EPI=0: QKV epilogue (bias + RoPE + scatter to Q/K/V).  EPI=1: dense epilogue (bias, f32 out).
template<int EPI>
__global__ __launch_bounds__(256) void k_gemm_bt(
    const __hip_bfloat16* __restrict__ A,
    const __hip_bfloat16* __restrict__ Bt,
    int K,
    const float* __restrict__ bias,
    const int* __restrict__ pos_ids,
    __hip_bfloat16* __restrict__ Qb,
    __hip_bfloat16* __restrict__ Kb,
    __hip_bfloat16* __restrict__ Vb,
    float* __restrict__ outF) {
  __shared__ char lds[16384];
  char* lA = lds;
  char* lB = lds + 8192;
  const int t = threadIdx.x, lane = t & 63, w = t >> 6;
  const int wr = w >> 1, wc = w & 1, g = lane >> 4, c = lane & 15;
  const int bm = blockIdx.x, bn = blockIdx.y;
  const __hip_bfloat16* Abase = A  + (size_t)bm * 128 * K;
  const __hip_bfloat16* Bbase = Bt + (size_t)bn * 128 * K;
  f32x4 acc[4][4] = {};

  for (int k0 = 0; k0 < K; k0 += 32) {
    __syncthreads();
    #pragma unroll
    for (int i = 0; i < 2; ++i) {
      int idx = i*256 + t;
      int row = idx >> 2, u = idx & 3;
      int su = (u ^ ((row >> 1) & 3)) * 8;   // pre-swizzled source column (16B units)
      GLD16(Abase + (size_t)row*K + k0 + su, lA + (i*256 + w*64)*16);
      GLD16(Bbase + (size_t)row*K + k0 + su, lB + (i*256 + w*64)*16);
    }
    __syncthreads();
    bf16x8 af[4], bf[4];
    #pragma unroll
    for (int mi = 0; mi < 4; ++mi) {
      int row = wr*64 + mi*16 + c;
      af[mi] = *(const bf16x8*)(lA + row*64 + ((g ^ ((row >> 1) & 3)) * 16));
    }
    #pragma unroll
    for (int ni = 0; ni < 4; ++ni) {
      int row = wc*64 + ni*16 + c;
      bf[ni] = *(const bf16x8*)(lB + row*64 + ((g ^ ((row >> 1) & 3)) * 16));
    }
    #pragma unroll
    for (int mi = 0; mi < 4; ++mi)
      #pragma unroll
      for (int ni = 0; ni < 4; ++ni)
        acc[mi][ni] = __builtin_amdgcn_mfma_f32_16x16x32_bf16(af[mi], bf[ni], acc[mi][ni], 0, 0, 0);
  }

  if (EPI == 0) {
    // cols of this block: n = bn*128 + (wc*64 + ni*16 + c); block is exactly one of q/k/v of one head
    const int btype = bn % 3, h = bn / 3;
    #pragma unroll
    for (int mi = 0; mi < 4; ++mi) {
      const int mrow0 = bm*128 + wr*64 + mi*16 + g*4;
      if (btype == 2) {
        #pragma unroll
        for (int ni = 0; ni < 4; ++ni) {
          const int d = wc*64 + ni*16 + c;
          const float bv = bias[bn*128 + d];
          #pragma unroll
          for (int j = 0; j < 4; ++j) {
            int m = mrow0 + j; int b = m >> 11, s = m & 2047;
            Vb[((size_t)(b*H_ + h)*S_ + s)*HD_ + d] = __float2bfloat16(acc[mi][ni][j] + bv);
          }
        }
      } else {
        __hip_bfloat16* op = (btype == 0) ? Qb : Kb;
        if (wc == 0) {
          // ni=0 holds d=c, ni=1 holds d=16+c : the RoPE pair lives in the same lane
          const float b0 = bias[bn*128 + c];
          const float b1 = bias[bn*128 + 16 + c];
          const float invf = __expf(-(float)c * LN10000_OVER16);
          #pragma unroll
          for (int j = 0; j < 4; ++j) {
            int m = mrow0 + j; int b = m >> 11, s = m & 2047;
            float ang = (float)pos_ids[m] * invf;
            float sv, cv; sincosf(ang, &sv, &cv);
            float x1 = acc[mi][0][j] + b0, x2 = acc[mi][1][j] + b1;
            size_t rb = ((size_t)(b*H_ + h)*S_ + s)*HD_;
            op[rb + c]      = __float2bfloat16(x1*cv - x2*sv);
            op[rb + 16 + c] = __float2bfloat16(x2*cv + x1*sv);
          }
          #pragma unroll
          for (int ni = 2; ni < 4; ++ni) {
            const int d = ni*16 + c;
            const float bv = bias[bn*128 + d];
            #pragma unroll
            for (int j = 0; j < 4; ++j) {
              int m = mrow0 + j; int b = m >> 11, s = m & 2047;
              op[((size_t)(b*H_ + h)*S_ + s)*HD_ + d] = __float2bfloat16(acc[mi][ni][j] + bv);
            }
          }
        } else {
          #pragma unroll
          for (int ni = 0; ni < 4; ++ni) {
            const int d = 64 + ni*16 + c;
            const float bv = bias[bn*128 + d];
            #pragma unroll
            for (int j = 0; j < 4; ++j) {
              int m = mrow0 + j; int b = m >> 11, s = m & 2047;
              op[((size_t)(b*H_ + h)*S_ + s)*HD_ + d] = __float2bfloat16(acc[mi][ni][j] + bv);
            }
          }
        }
      }
    }
  } else {
    #pragma unroll
    for (int mi = 0; mi < 4; ++mi) {
      const int mrow0 = bm*128 + wr*64 + mi*16 + g*4;
      #pragma unroll
      for (int ni = 0; ni < 4; ++ni) {
        const int n = bn*128 + wc*64 + ni*16 + c;
        const float bv = bias[n];
        #pragma unroll
        for (int j = 0; j < 4; ++j) {
          int m = mrow0 + j;
          outF[(size_t)m*HID_ + n] = acc[mi][ni][j] + bv;
        }
      }
    }
  }
}

// ---------------- flash attention ----------------
// grid (B*H, 16). 128 q-rows per block, 4 waves x 32 rows. KBLK=64.
__global__ __launch_bounds__(256) void k_attn(
    const __hip_bfloat16* __restrict__ Qb,
    const __hip_bfloat16* __restrict__ Kb,
    const __hip_bfloat16* __restrict__ VTb,
    __hip_bfloat16* __restrict__ Ob) {
  __shared__ char lds[49152];
  char* lK = lds;                 // [64 rows][16 units(16B)] swizzled  (16 KiB)
  char* lV = lds + 16384;         // [128 rows][8 units]     swizzled  (16 KiB)
  char* lPw = lds + 32768 + (threadIdx.x >> 6) * 4096;  // per-wave P [32][8 units]
  const int t = threadIdx.x, lane = t & 63, w = t >> 6, g = lane >> 4, c = lane & 15;
  const int bh = blockIdx.x, qt = 15 - blockIdx.y;  // heavy blocks dispatch first
  const size_t base = (size_t)bh * S_ * HD_;
  const __hip_bfloat16* Qp = Qb + base;
  const __hip_bfloat16* Kp = Kb + base;
  const __hip_bfloat16* Vp = VTb + base;

  // Q fragments in registers (A-operand): lane holds Q[qrow=..+c][d = kf*32 + g*8 .. +8]
  bf16x8 qf[2][4];
  #pragma unroll
  for (int mi = 0; mi < 2; ++mi) {
    int qrow = qt*128 + w*32 + mi*16 + c;
    #pragma unroll
    for (int kf = 0; kf < 4; ++kf)
      qf[mi][kf] = *(const bf16x8*)(Qp + (size_t)qrow*HD_ + kf*32 + g*8);
  }

  f32x4 oacc[2][8] = {};
  float mrun[2][4], lrun[2][4];
  #pragma unroll
  for (int mi = 0; mi < 2; ++mi)
    #pragma unroll
    for (int j = 0; j < 4; ++j) { mrun[mi][j] = -3.0e38f; lrun[mi][j] = 0.f; }

  const int nkt = qt*2 + 2;
  const float scale = 0.08838834764831845f;  // 1/sqrt(128)

  for (int kt = 0; kt < nkt; ++kt) {
    __syncthreads();  // prior tile fully consumed before overwrite
    #pragma unroll
    for (int i = 0; i < 4; ++i) {    // K tile: 64 rows x 256B
      int idx = i*256 + t;
      int row = idx >> 4, u = idx & 15;
      GLD16(Kp + (size_t)(kt*64 + row)*HD_ + ((u ^ (row & 15)) * 8),
            lK + (i*256 + w*64)*16);
    }
    #pragma unroll
    for (int i = 0; i < 4; ++i) {    // VT tile: 128 rows x 128B
      int idx = i*256 + t;
      int dr = idx >> 3, u = idx & 7;
      GLD16(Vp + (size_t)dr*S_ + kt*64 + ((u ^ (dr & 7)) * 8),
            lV + (i*256 + w*64)*16);
    }
    __syncthreads();

    // ---- S = Q K^T ----
    f32x4 sacc[2][4] = {};
    #pragma unroll
    for (int ni = 0; ni < 4; ++ni) {
      int krow = ni*16 + c;
      bf16x8 kfr[4];
      #pragma unroll
      for (int kf = 0; kf < 4; ++kf)
        kfr[kf] = *(const bf16x8*)(lK + krow*256 + (((kf*4 + g) ^ (krow & 15)) * 16));
      #pragma unroll
      for (int mi = 0; mi < 2; ++mi)
        #pragma unroll
        for (int kf = 0; kf < 4; ++kf)
          sacc[mi][ni] = __builtin_amdgcn_mfma_f32_16x16x32_bf16(qf[mi][kf], kfr[kf], sacc[mi][ni], 0, 0, 0);
    }

    // ---- online softmax (rows live across 16 lanes of a group) ----
    #pragma unroll
    for (int mi = 0; mi < 2; ++mi) {
      #pragma unroll
      for (int j = 0; j < 4; ++j) {
        int row = qt*128 + w*32 + mi*16 + g*4 + j;
        float mx = -3.0e38f;
        #pragma unroll
        for (int ni = 0; ni < 4; ++ni) {
          int col = kt*64 + ni*16 + c;
          float sc = sacc[mi][ni][j] * scale;
          if (col > row) sc = -3.0e38f;
          sacc[mi][ni][j] = sc;
          mx = fmaxf(mx, sc);
        }
        mx = fmaxf(mx, __shfl_xor(mx, 1));
        mx = fmaxf(mx, __shfl_xor(mx, 2));
        mx = fmaxf(mx, __shfl_xor(mx, 4));
        mx = fmaxf(mx, __shfl_xor(mx, 8));
        float mnew = fmaxf(mrun[mi][j], mx);
        float fac = __expf(mrun[mi][j] - mnew);
        mrun[mi][j] = mnew;
        float ls = 0.f;
        int prow = mi*16 + g*4 + j;
        #pragma unroll
        for (int ni = 0; ni < 4; ++ni) {
          float pv = __expf(sacc[mi][ni][j] - mnew);
          ls += pv;
          int cu = (ni*2 + (c >> 3)) ^ (prow & 7);
          *(__hip_bfloat16*)(lPw + prow*128 + cu*16 + (c & 7)*2) = __float2bfloat16(pv);
        }
        ls += __shfl_xor(ls, 1);
        ls += __shfl_xor(ls, 2);
        ls += __shfl_xor(ls, 4);
        ls += __shfl_xor(ls, 8);
        lrun[mi][j] = lrun[mi][j]*fac + ls;
        #pragma unroll
        for (int nio = 0; nio < 8; ++nio) oacc[mi][nio][j] *= fac;
      }
    }
    __syncthreads();  // P visible (and keeps waves phase-locked)

    // ---- O += P V ----
    bf16x8 paf[2][2];
    #pragma unroll
    for (int mi = 0; mi < 2; ++mi)
      #pragma unroll
      for (int kc = 0; kc < 2; ++kc) {
        int prow = mi*16 + c;
        paf[mi][kc] = *(const bf16x8*)(lPw + prow*128 + (((kc*4 + g) ^ (prow & 7)) * 16));
      }
    #pragma unroll
    for (int nio = 0; nio < 8; ++nio) {
      int dr = nio*16 + c;
      bf16x8 v0 = *(const bf16x8*)(lV + dr*128 + (((g)     ^ (dr & 7)) * 16));
      bf16x8 v1 = *(const bf16x8*)(lV + dr*128 + (((4 + g) ^ (dr & 7)) * 16));
      #pragma unroll
      for (int mi = 0; mi < 2; ++mi) {
        oacc[mi][nio] = __builtin_amdgcn_mfma_f32_16x16x32_bf16(paf[mi][0], v0, oacc[mi][nio], 0, 0, 0);
        oacc[mi][nio] = __builtin_amdgcn_mfma_f32_16x16x32_bf16(paf[mi][1], v1, oacc[mi][nio], 0, 0, 0);
      }
    }
  }

  // ---- write attn out: [b][s][h*128 + d] bf16 ----
  const int b = bh >> 4, h = bh & 15;
  #pragma unroll
  for (int mi = 0; mi < 2; ++mi)
    #pragma unroll
    for (int j = 0; j < 4; ++j) {
      int s = qt*128 + w*32 + mi*16 + g*4 + j;
      float inv = 1.0f / lrun[mi][j];
      size_t rb = ((size_t)(b*S_ + s))*HID_ + h*HD_;
      #pragma unroll
      for (int nio = 0; nio < 8; ++nio)
        Ob[rb + nio*16 + c] = __float2bfloat16(oacc[mi][nio][j] * inv);
    }
}

// ---------------- host launch ----------------
extern "C" void kernel_launch(void* const* d_in, const int* in_sizes, int n_in,
                              void* d_out, int out_size, void* d_ws, size_t ws_size,
                              hipStream_t stream) {
  const float* hs   = (const float*)d_in[0];
  const int*   pos  = (const int*)d_in[1];
  // d_in[2] = attention_mask (triu k=1) — causal, applied analytically
  const float* Wqkv = (const float*)d_in[3];
  const float* bqkv = (const float*)d_in[4];
  const float* Wd   = (const float*)d_in[5];
  const float* bd   = (const float*)d_in[6];
  float* out = (float*)d_out;

  char* ws = (char*)d_ws;
  __hip_bfloat16* hsb = (__hip_bfloat16*)(ws);                 // 16 MiB: hidden bf16 [4096][2048]
  __hip_bfloat16* WqT = (__hip_bfloat16*)(ws + 16777216);      // 24 MiB: W_qkv^T bf16 [6144][2048]
  __hip_bfloat16* WdT = (__hip_bfloat16*)(ws + 41943040);      //  8 MiB: W_dense^T bf16 [2048][2048]
  __hip_bfloat16* Qb  = (__hip_bfloat16*)(ws + 50331648);      // 16 MiB: Q (rope'd) [bh][S][HD]
  __hip_bfloat16* Kb  = (__hip_bfloat16*)(ws + 67108864);      // 16 MiB: K (rope'd) [bh][S][HD]
  __hip_bfloat16* VTb = (__hip_bfloat16*)(ws + 83886080);      // 16 MiB: V^T [bh][HD][S]
  __hip_bfloat16* Vb  = (__hip_bfloat16*)(ws + 100663296);     // 16 MiB: V then attn-out [b][s][hid]

  k_cvt_bf16<<<8192, 256, 0, stream>>>(hs, hsb, (M_*HID_)/4);
  k_transpose_w<<<dim3(HID_/32, NQKV_/32), dim3(32, 8), 0, stream>>>(Wqkv, WqT, HID_, NQKV_);
  k_transpose_w<<<dim3(HID_/32, HID_/32), dim3(32, 8), 0, stream>>>(Wd, WdT, HID_, HID_);
  k_gemm_bt<0><<<dim3(M_/128, NQKV_/128), 256, 0, stream>>>(hsb, WqT, HID_, bqkv, pos, Qb, Kb, Vb, nullptr);
  k_transpose_v<<<dim3(S_/32, HD_/32, B_*H_), dim3(32, 8), 0, stream>>>(Vb, VTb);
  k_attn<<<dim3(B_*H_, 16), 256, 0, stream>>>(Qb, Kb, VTb, Vb);
  k_gemm_bt<1><<<dim3(M_/128, HID_/128), 256, 0, stream>>>(Vb, WdT, HID_, bd, nullptr, nullptr, nullptr, nullptr, out);
}

// Round 2
// 333.958 us; speedup vs baseline: 1.0315x; 1.0315x over previous
//
#include <hip/hip_runtime.h>
#include <hip/hip_bf16.h>

typedef __attribute__((ext_vector_type(4))) float f32x4;
typedef __attribute__((ext_vector_type(8))) __bf16 bf16x8;

#define B_    2
#define S_    2048
#define HID_  2048
#define H_    16
#define HD_   128
#define M_    (B_*S_)    // 4096
#define NQKV_ 6144
#define LN10000_OVER16 0.5756462732485114f

#define GLD16(gp, lp) \
  __builtin_amdgcn_global_load_lds((const __attribute__((address_space(1))) void*)(gp), \
                                   (__attribute__((address_space(3))) void*)(lp), 16, 0, 0)

// ---------------- f32 -> bf16 flat convert (vectorized) ----------------
__global__ __launch_bounds__(256) void k_cvt_bf16(const float* __restrict__ x,
                                                  __hip_bfloat16* __restrict__ y, int n4) {
  int i = blockIdx.x * 256 + threadIdx.x;
  if (i >= n4) return;
  float4 v = ((const float4*)x)[i];
  union { __hip_bfloat16 h[4]; uint2 u; } o;
  o.h[0] = __float2bfloat16(v.x); o.h[1] = __float2bfloat16(v.y);
  o.h[2] = __float2bfloat16(v.z); o.h[3] = __float2bfloat16(v.w);
  *(uint2*)(y + 4*(size_t)i) = o.u;
}

// ---------------- W [K][N] f32 -> Wt [N][K] bf16 ----------------
__global__ __launch_bounds__(256) void k_transpose_w(const float* __restrict__ W,
                                                     __hip_bfloat16* __restrict__ Wt,
                                                     int K, int N) {
  __shared__ float tile[32][33];
  int k0 = blockIdx.x * 32, n0 = blockIdx.y * 32;
  int tx = threadIdx.x, ty = threadIdx.y;  // 32 x 8
  #pragma unroll
  for (int i = 0; i < 4; ++i)
    tile[ty + i*8][tx] = W[(size_t)(k0 + ty + i*8)*N + n0 + tx];
  __syncthreads();
  #pragma unroll
  for (int i = 0; i < 4; ++i)
    Wt[(size_t)(n0 + ty + i*8)*K + k0 + tx] = __float2bfloat16(tile[tx][ty + i*8]);
}

// ---------------- V [bh][S][HD] -> VT [bh][HD][S] (bf16) ----------------
__global__ __launch_bounds__(256) void k_transpose_v(const __hip_bfloat16* __restrict__ V,
                                                     __hip_bfloat16* __restrict__ VT) {
  __shared__ __hip_bfloat16 tile[32][33];
  int s0 = blockIdx.x * 32, d0 = blockIdx.y * 32, bh = blockIdx.z;
  int tx = threadIdx.x, ty = threadIdx.y;  // 32 x 8
  size_t base = (size_t)bh * S_ * HD_;
  #pragma unroll
  for (int i = 0; i < 4; ++i)
    tile[ty + i*8][tx] = V[base + (size_t)(s0 + ty + i*8)*HD_ + d0 + tx];
  __syncthreads();
  #pragma unroll
  for (int i = 0; i < 4; ++i)
    VT[base + (size_t)(d0 + ty + i*8)*S_ + s0 + tx] = tile[tx][ty + i*8];
}

// ================= 8-phase 256x256 QKV GEMM (T1+T2+T3+T4+T5) =================
// C[M=4096, N=6144] = A[M][K=2048] @ Bt[N][K]^T, epilogue bias+RoPE+scatter.
// 8 waves (2M x 4N), per-wave 128x64 out. BK=64. LDS 128 KiB double-buffered.
// Staging for tile T: A-halves at (T-2).p3, B0 at (T-1).p0, B1 at (T-1).p1.
// Single boundary wait vmcnt(4): only (T+1).A may be in flight.

#define STG(gbase, half, kt, ldsOff) do {                                        \
    _Pragma("unroll")                                                            \
    for (int L_ = 0; L_ < 2; ++L_)                                               \
      GLD16((gbase) + (size_t)((half)*128 + L_*64 + srow)*HID_ + (kt)*64 + su*8, \
            lds + (ldsOff) + (half)*16384 + L_*8192 + t*16);                     \
  } while (0)

#define RDA(mh, boff) do {                                                       \
    _Pragma("unroll") for (int q_ = 0; q_ < 4; ++q_)                             \
      _Pragma("unroll") for (int ks_ = 0; ks_ < 2; ++ks_)                        \
        af[q_][ks_] = *(const bf16x8*)(lds + (boff) + aBase + ((mh)*4+q_)*2048   \
                                       + (((ks_*4+g) ^ key)*16));                \
  } while (0)

#define RDB(nh, boff) do {                                                       \
    _Pragma("unroll") for (int n_ = 0; n_ < 2; ++n_)                             \
      _Pragma("unroll") for (int ks_ = 0; ks_ < 2; ++ks_)                        \
        bf[n_][ks_] = *(const bf16x8*)(lds + (boff) + bBase + ((nh)*2+n_)*2048   \
                                       + (((ks_*4+g) ^ key)*16));                \
  } while (0)

#define MM(mh, nh) do {                                                          \
    _Pragma("unroll") for (int q_ = 0; q_ < 4; ++q_)                             \
      _Pragma("unroll") for (int n_ = 0; n_ < 2; ++n_)                           \
        _Pragma("unroll") for (int ks_ = 0; ks_ < 2; ++ks_)                      \
          acc[(mh)*4+q_][(nh)*2+n_] = __builtin_amdgcn_mfma_f32_16x16x32_bf16(   \
              af[q_][ks_], bf[n_][ks_], acc[(mh)*4+q_][(nh)*2+n_], 0, 0, 0);     \
  } while (0)

__global__ __launch_bounds__(512, 2) void k_gemm8_qkv(
    const __hip_bfloat16* __restrict__ A,
    const __hip_bfloat16* __restrict__ Bt,
    const float* __restrict__ bias,
    const int* __restrict__ pos_ids,
    __hip_bfloat16* __restrict__ Qb,
    __hip_bfloat16* __restrict__ Kb,
    __hip_bfloat16* __restrict__ Vb) {
  extern __shared__ char lds[];   // 131072 B: 2 bufs x {A0,A1,B0,B1} x 16 KiB
  const int nk = HID_ / 64;       // 32
  const int t = threadIdx.x, lane = t & 63, g = lane >> 4, c = lane & 15;
  const int w = t >> 6, wr = w >> 2, wc = w & 3;

  // XCD-aware swizzle: nwg = 16*24 = 384, 384 % 8 == 0 (bijective)
  const int bid = blockIdx.x;
  const int swz = (bid & 7) * 48 + (bid >> 3);
  const int bm = swz / 24, bn = swz % 24;

  const __hip_bfloat16* Ab = A  + (size_t)bm * 256 * HID_;
  const __hip_bfloat16* Bb = Bt + (size_t)bn * 256 * HID_;

  // staging per-thread constants: row-in-64-block, pre-swizzled source unit
  const int srow = t >> 3;
  const int su   = (t & 7) ^ (srow & 7);
  // ds_read bases (swizzle key reduces to c&7: row low bits == c low bits)
  const int aBase = wr*16384 + c*128;
  const int bBase = 32768 + (wc >> 1)*16384 + ((wc & 1)*64 + c)*128;
  const int key = c & 7;

  f32x4 acc[8][4] = {};
  bf16x8 af[4][2], bf[2][2];

  // ---- prologue: T0 fully, T1 A-halves ----
  STG(Ab, 0, 0, 0);      STG(Ab, 1, 0, 0);
  STG(Bb, 0, 0, 32768);  STG(Bb, 1, 0, 32768);
  STG(Ab, 0, 1, 65536);  STG(Ab, 1, 1, 65536);
  asm volatile("s_waitcnt vmcnt(4)" ::: "memory");
  __builtin_amdgcn_s_barrier();

  for (int kt = 0; kt < nk; ++kt) {
    const int cb = (kt & 1) * 65536;
    const int nb = cb ^ 65536;

    // ---- p0: quadrant (mh0, nh0) ----
    RDA(0, cb); RDB(0, cb);
    if (kt + 1 < nk) STG(Bb, 0, kt + 1, nb + 32768);
    __builtin_amdgcn_s_barrier();
    __builtin_amdgcn_s_setprio(1);
    MM(0, 0);
    __builtin_amdgcn_s_setprio(0);
    __builtin_amdgcn_s_barrier();

    // ---- p1: (mh0, nh1) ----
    RDB(1, cb);
    if (kt + 1 < nk) STG(Bb, 1, kt + 1, nb + 32768);
    __builtin_amdgcn_s_barrier();
    __builtin_amdgcn_s_setprio(1);
    MM(0, 1);
    __builtin_amdgcn_s_setprio(0);
    __builtin_amdgcn_s_barrier();

    // ---- p2: (mh1, nh1) ----
    RDA(1, cb);
    __builtin_amdgcn_s_barrier();
    __builtin_amdgcn_s_setprio(1);
    MM(1, 1);
    __builtin_amdgcn_s_setprio(0);
    __builtin_amdgcn_s_barrier();

    // ---- p3: (mh1, nh0); re-stage current buffer's A for tile kt+2 ----
    RDB(0, cb);
    asm volatile("s_waitcnt lgkmcnt(0)" ::: "memory");   // my reads landed
    __builtin_amdgcn_sched_barrier(0);
    __builtin_amdgcn_s_barrier();                        // all waves done reading cb
    if (kt + 2 < nk) { STG(Ab, 0, kt + 2, cb); STG(Ab, 1, kt + 2, cb); }
    __builtin_amdgcn_s_setprio(1);
    MM(1, 0);
    __builtin_amdgcn_s_setprio(0);
    if (kt + 2 < nk) asm volatile("s_waitcnt vmcnt(4)" ::: "memory");
    else             asm volatile("s_waitcnt vmcnt(0)" ::: "memory");
    __builtin_amdgcn_s_barrier();
  }

  // ---- epilogue: bias + RoPE + scatter to Q/K/V [bh][S][HD] bf16 ----
  #pragma unroll
  for (int mi = 0; mi < 8; ++mi) {
    const int m0 = bm*256 + wr*128 + mi*16 + g*4;
    #pragma unroll
    for (int ni = 0; ni < 4; ++ni) {
      const int n = bn*256 + wc*64 + ni*16 + c;
      const int h = n / 384;
      const int r = n - h*384;
      const int typ = r >> 7;       // 0=q 1=k 2=v  (wave-uniform per frag)
      const int d = r & 127;
      if (typ == 2) {
        const float bv = bias[n];
        #pragma unroll
        for (int j = 0; j < 4; ++j) {
          int m = m0 + j; int b = m >> 11, s = m & 2047;
          Vb[((size_t)(b*H_ + h)*S_ + s)*HD_ + d] = __float2bfloat16(acc[mi][ni][j] + bv);
        }
      } else {
        __hip_bfloat16* op = typ ? Kb : Qb;
        if (d < 16) {               // rot low half; partner (d+16) is frag ni+1
          const float b0 = bias[n], b1 = bias[n + 16];
          const float invf = __expf(-(float)d * LN10000_OVER16);
          #pragma unroll
          for (int j = 0; j < 4; ++j) {
            int m = m0 + j; int b = m >> 11, s = m & 2047;
            float ang = (float)pos_ids[m] * invf;
            float sv, cv; sincosf(ang, &sv, &cv);
            float x1 = acc[mi][ni][j] + b0, x2 = acc[mi][ni + 1][j] + b1;
            size_t rb = ((size_t)(b*H_ + h)*S_ + s)*HD_;
            op[rb + d]      = __float2bfloat16(x1*cv - x2*sv);
            op[rb + d + 16] = __float2bfloat16(x2*cv + x1*sv);
          }
        } else if (d >= 32) {       // pass-through
          const float bv = bias[n];
          #pragma unroll
          for (int j = 0; j < 4; ++j) {
            int m = m0 + j; int b = m >> 11, s = m & 2047;
            op[((size_t)(b*H_ + h)*S_ + s)*HD_ + d] = __float2bfloat16(acc[mi][ni][j] + bv);
          }
        } // 16 <= d < 32: written by partner frag
      }
    }
  }
}

// ---------------- dense GEMM (128^2, unchanged this round) ----------------
template<int EPI>
__global__ __launch_bounds__(256) void k_gemm_bt(
    const __hip_bfloat16* __restrict__ A,
    const __hip_bfloat16* __restrict__ Bt,
    int K,
    const float* __restrict__ bias,
    float* __restrict__ outF) {
  __shared__ char lds[16384];
  char* lA = lds;
  char* lB = lds + 8192;
  const int t = threadIdx.x, lane = t & 63, w = t >> 6;
  const int wr = w >> 1, wc = w & 1, g = lane >> 4, c = lane & 15;
  const int bm = blockIdx.x, bn = blockIdx.y;
  const __hip_bfloat16* Abase = A  + (size_t)bm * 128 * K;
  const __hip_bfloat16* Bbase = Bt + (size_t)bn * 128 * K;
  f32x4 acc[4][4] = {};

  for (int k0 = 0; k0 < K; k0 += 32) {
    __syncthreads();
    #pragma unroll
    for (int i = 0; i < 2; ++i) {
      int idx = i*256 + t;
      int row = idx >> 2, u = idx & 3;
      int su = (u ^ ((row >> 1) & 3)) * 8;
      GLD16(Abase + (size_t)row*K + k0 + su, lA + (i*256 + w*64)*16);
      GLD16(Bbase + (size_t)row*K + k0 + su, lB + (i*256 + w*64)*16);
    }
    __syncthreads();
    bf16x8 af[4], bfr[4];
    #pragma unroll
    for (int mi = 0; mi < 4; ++mi) {
      int row = wr*64 + mi*16 + c;
      af[mi] = *(const bf16x8*)(lA + row*64 + ((g ^ ((row >> 1) & 3)) * 16));
    }
    #pragma unroll
    for (int ni = 0; ni < 4; ++ni) {
      int row = wc*64 + ni*16 + c;
      bfr[ni] = *(const bf16x8*)(lB + row*64 + ((g ^ ((row >> 1) & 3)) * 16));
    }
    #pragma unroll
    for (int mi = 0; mi < 4; ++mi)
      #pragma unroll
      for (int ni = 0; ni < 4; ++ni)
        acc[mi][ni] = __builtin_amdgcn_mfma_f32_16x16x32_bf16(af[mi], bfr[ni], acc[mi][ni], 0, 0, 0);
  }

  #pragma unroll
  for (int mi = 0; mi < 4; ++mi) {
    const int mrow0 = bm*128 + wr*64 + mi*16 + g*4;
    #pragma unroll
    for (int ni = 0; ni < 4; ++ni) {
      const int n = bn*128 + wc*64 + ni*16 + c;
      const float bv = bias[n];
      #pragma unroll
      for (int j = 0; j < 4; ++j) {
        int m = mrow0 + j;
        outF[(size_t)m*HID_ + n] = acc[mi][ni][j] + bv;
      }
    }
  }
}

// ---------------- flash attention (unchanged) ----------------
__global__ __launch_bounds__(256) void k_attn(
    const __hip_bfloat16* __restrict__ Qb,
    const __hip_bfloat16* __restrict__ Kb,
    const __hip_bfloat16* __restrict__ VTb,
    __hip_bfloat16* __restrict__ Ob) {
  __shared__ char lds[49152];
  char* lK = lds;
  char* lV = lds + 16384;
  char* lPw = lds + 32768 + (threadIdx.x >> 6) * 4096;
  const int t = threadIdx.x, lane = t & 63, w = t >> 6, g = lane >> 4, c = lane & 15;
  const int bh = blockIdx.x, qt = 15 - blockIdx.y;
  const size_t base = (size_t)bh * S_ * HD_;
  const __hip_bfloat16* Qp = Qb + base;
  const __hip_bfloat16* Kp = Kb + base;
  const __hip_bfloat16* Vp = VTb + base;

  bf16x8 qf[2][4];
  #pragma unroll
  for (int mi = 0; mi < 2; ++mi) {
    int qrow = qt*128 + w*32 + mi*16 + c;
    #pragma unroll
    for (int kf = 0; kf < 4; ++kf)
      qf[mi][kf] = *(const bf16x8*)(Qp + (size_t)qrow*HD_ + kf*32 + g*8);
  }

  f32x4 oacc[2][8] = {};
  float mrun[2][4], lrun[2][4];
  #pragma unroll
  for (int mi = 0; mi < 2; ++mi)
    #pragma unroll
    for (int j = 0; j < 4; ++j) { mrun[mi][j] = -3.0e38f; lrun[mi][j] = 0.f; }

  const int nkt = qt*2 + 2;
  const float scale = 0.08838834764831845f;

  for (int kt = 0; kt < nkt; ++kt) {
    __syncthreads();
    #pragma unroll
    for (int i = 0; i < 4; ++i) {
      int idx = i*256 + t;
      int row = idx >> 4, u = idx & 15;
      GLD16(Kp + (size_t)(kt*64 + row)*HD_ + ((u ^ (row & 15)) * 8),
            lK + (i*256 + w*64)*16);
    }
    #pragma unroll
    for (int i = 0; i < 4; ++i) {
      int idx = i*256 + t;
      int dr = idx >> 3, u = idx & 7;
      GLD16(Vp + (size_t)dr*S_ + kt*64 + ((u ^ (dr & 7)) * 8),
            lV + (i*256 + w*64)*16);
    }
    __syncthreads();

    f32x4 sacc[2][4] = {};
    #pragma unroll
    for (int ni = 0; ni < 4; ++ni) {
      int krow = ni*16 + c;
      bf16x8 kfr[4];
      #pragma unroll
      for (int kf = 0; kf < 4; ++kf)
        kfr[kf] = *(const bf16x8*)(lK + krow*256 + (((kf*4 + g) ^ (krow & 15)) * 16));
      #pragma unroll
      for (int mi = 0; mi < 2; ++mi)
        #pragma unroll
        for (int kf = 0; kf < 4; ++kf)
          sacc[mi][ni] = __builtin_amdgcn_mfma_f32_16x16x32_bf16(qf[mi][kf], kfr[kf], sacc[mi][ni], 0, 0, 0);
    }

    #pragma unroll
    for (int mi = 0; mi < 2; ++mi) {
      #pragma unroll
      for (int j = 0; j < 4; ++j) {
        int row = qt*128 + w*32 + mi*16 + g*4 + j;
        float mx = -3.0e38f;
        #pragma unroll
        for (int ni = 0; ni < 4; ++ni) {
          int col = kt*64 + ni*16 + c;
          float sc = sacc[mi][ni][j] * scale;
          if (col > row) sc = -3.0e38f;
          sacc[mi][ni][j] = sc;
          mx = fmaxf(mx, sc);
        }
        mx = fmaxf(mx, __shfl_xor(mx, 1));
        mx = fmaxf(mx, __shfl_xor(mx, 2));
        mx = fmaxf(mx, __shfl_xor(mx, 4));
        mx = fmaxf(mx, __shfl_xor(mx, 8));
        float mnew = fmaxf(mrun[mi][j], mx);
        float fac = __expf(mrun[mi][j] - mnew);
        mrun[mi][j] = mnew;
        float ls = 0.f;
        int prow = mi*16 + g*4 + j;
        #pragma unroll
        for (int ni = 0; ni < 4; ++ni) {
          float pv = __expf(sacc[mi][ni][j] - mnew);
          ls += pv;
          int cu = (ni*2 + (c >> 3)) ^ (prow & 7);
          *(__hip_bfloat16*)(lPw + prow*128 + cu*16 + (c & 7)*2) = __float2bfloat16(pv);
        }
        ls += __shfl_xor(ls, 1);
        ls += __shfl_xor(ls, 2);
        ls += __shfl_xor(ls, 4);
        ls += __shfl_xor(ls, 8);
        lrun[mi][j] = lrun[mi][j]*fac + ls;
        #pragma unroll
        for (int nio = 0; nio < 8; ++nio) oacc[mi][nio][j] *= fac;
      }
    }
    __syncthreads();

    bf16x8 paf[2][2];
    #pragma unroll
    for (int mi = 0; mi < 2; ++mi)
      #pragma unroll
      for (int kc = 0; kc < 2; ++kc) {
        int prow = mi*16 + c;
        paf[mi][kc] = *(const bf16x8*)(lPw + prow*128 + (((kc*4 + g) ^ (prow & 7)) * 16));
      }
    #pragma unroll
    for (int nio = 0; nio < 8; ++nio) {
      int dr = nio*16 + c;
      bf16x8 v0 = *(const bf16x8*)(lV + dr*128 + (((g)     ^ (dr & 7)) * 16));
      bf16x8 v1 = *(const bf16x8*)(lV + dr*128 + (((4 + g) ^ (dr & 7)) * 16));
      #pragma unroll
      for (int mi = 0; mi < 2; ++mi) {
        oacc[mi][nio] = __builtin_amdgcn_mfma_f32_16x16x32_bf16(paf[mi][0], v0, oacc[mi][nio], 0, 0, 0);
        oacc[mi][nio] = __builtin_amdgcn_mfma_f32_16x16x32_bf16(paf[mi][1], v1, oacc[mi][nio], 0, 0, 0);
      }
    }
  }

  const int b = bh >> 4, h = bh & 15;
  #pragma unroll
  for (int mi = 0; mi < 2; ++mi)
    #pragma unroll
    for (int j = 0; j < 4; ++j) {
      int s = qt*128 + w*32 + mi*16 + g*4 + j;
      float inv = 1.0f / lrun[mi][j];
      size_t rb = ((size_t)(b*S_ + s))*HID_ + h*HD_;
      #pragma unroll
      for (int nio = 0; nio < 8; ++nio)
        Ob[rb + nio*16 + c] = __float2bfloat16(oacc[mi][nio][j] * inv);
    }
}

// ---------------- host launch ----------------
extern "C" void kernel_launch(void* const* d_in, const int* in_sizes, int n_in,
                              void* d_out, int out_size, void* d_ws, size_t ws_size,
                              hipStream_t stream) {
  const float* hs   = (const float*)d_in[0];
  const int*   pos  = (const int*)d_in[1];
  const float* Wqkv = (const float*)d_in[3];
  const float* bqkv = (const float*)d_in[4];
  const float* Wd   = (const float*)d_in[5];
  const float* bd   = (const float*)d_in[6];
  float* out = (float*)d_out;

  char* ws = (char*)d_ws;
  __hip_bfloat16* hsb = (__hip_bfloat16*)(ws);
  __hip_bfloat16* WqT = (__hip_bfloat16*)(ws + 16777216);
  __hip_bfloat16* WdT = (__hip_bfloat16*)(ws + 41943040);
  __hip_bfloat16* Qb  = (__hip_bfloat16*)(ws + 50331648);
  __hip_bfloat16* Kb  = (__hip_bfloat16*)(ws + 67108864);
  __hip_bfloat16* VTb = (__hip_bfloat16*)(ws + 83886080);
  __hip_bfloat16* Vb  = (__hip_bfloat16*)(ws + 100663296);

  hipFuncSetAttribute((const void*)k_gemm8_qkv,
                      hipFuncAttributeMaxDynamicSharedMemorySize, 131072);

  k_cvt_bf16<<<8192, 256, 0, stream>>>(hs, hsb, (M_*HID_)/4);
  k_transpose_w<<<dim3(HID_/32, NQKV_/32), dim3(32, 8), 0, stream>>>(Wqkv, WqT, HID_, NQKV_);
  k_transpose_w<<<dim3(HID_/32, HID_/32), dim3(32, 8), 0, stream>>>(Wd, WdT, HID_, HID_);
  k_gemm8_qkv<<<384, 512, 131072, stream>>>(hsb, WqT, bqkv, pos, Qb, Kb, Vb);
  k_transpose_v<<<dim3(S_/32, HD_/32, B_*H_), dim3(32, 8), 0, stream>>>(Vb, VTb);
  k_attn<<<dim3(B_*H_, 16), 256, 0, stream>>>(Qb, Kb, VTb, Vb);
  k_gemm_bt<1><<<dim3(M_/128, HID_/128), 256, 0, stream>>>(Vb, WdT, HID_, bd, out);
}

// Round 3
// 307.109 us; speedup vs baseline: 1.1216x; 1.0874x over previous
//
#include <hip/hip_runtime.h>
#include <hip/hip_bf16.h>

typedef __attribute__((ext_vector_type(4))) float f32x4;
typedef __attribute__((ext_vector_type(8))) __bf16 bf16x8;

#define B_    2
#define S_    2048
#define HID_  2048
#define H_    16
#define HD_   128
#define M_    (B_*S_)    // 4096
#define NQKV_ 6144
#define LN10000_OVER16 0.5756462732485114f

#define GLD16(gp, lp) \
  __builtin_amdgcn_global_load_lds((const __attribute__((address_space(1))) void*)(gp), \
                                   (__attribute__((address_space(3))) void*)(lp), 16, 0, 0)

// ---------------- f32 -> bf16 flat convert (vectorized) ----------------
__global__ __launch_bounds__(256) void k_cvt_bf16(const float* __restrict__ x,
                                                  __hip_bfloat16* __restrict__ y, int n4) {
  int i = blockIdx.x * 256 + threadIdx.x;
  if (i >= n4) return;
  float4 v = ((const float4*)x)[i];
  union { __hip_bfloat16 h[4]; uint2 u; } o;
  o.h[0] = __float2bfloat16(v.x); o.h[1] = __float2bfloat16(v.y);
  o.h[2] = __float2bfloat16(v.z); o.h[3] = __float2bfloat16(v.w);
  *(uint2*)(y + 4*(size_t)i) = o.u;
}

// ---------------- W [K][N] f32 -> Wt [N][K] bf16 ----------------
__global__ __launch_bounds__(256) void k_transpose_w(const float* __restrict__ W,
                                                     __hip_bfloat16* __restrict__ Wt,
                                                     int K, int N) {
  __shared__ float tile[32][33];
  int k0 = blockIdx.x * 32, n0 = blockIdx.y * 32;
  int tx = threadIdx.x, ty = threadIdx.y;  // 32 x 8
  #pragma unroll
  for (int i = 0; i < 4; ++i)
    tile[ty + i*8][tx] = W[(size_t)(k0 + ty + i*8)*N + n0 + tx];
  __syncthreads();
  #pragma unroll
  for (int i = 0; i < 4; ++i)
    Wt[(size_t)(n0 + ty + i*8)*K + k0 + tx] = __float2bfloat16(tile[tx][ty + i*8]);
}

// ---------------- V [bh][S][HD] -> VT [bh][HD][S] (bf16) ----------------
__global__ __launch_bounds__(256) void k_transpose_v(const __hip_bfloat16* __restrict__ V,
                                                     __hip_bfloat16* __restrict__ VT) {
  __shared__ __hip_bfloat16 tile[32][33];
  int s0 = blockIdx.x * 32, d0 = blockIdx.y * 32, bh = blockIdx.z;
  int tx = threadIdx.x, ty = threadIdx.y;  // 32 x 8
  size_t base = (size_t)bh * S_ * HD_;
  #pragma unroll
  for (int i = 0; i < 4; ++i)
    tile[ty + i*8][tx] = V[base + (size_t)(s0 + ty + i*8)*HD_ + d0 + tx];
  __syncthreads();
  #pragma unroll
  for (int i = 0; i < 4; ++i)
    VT[base + (size_t)(d0 + ty + i*8)*S_ + s0 + tx] = tile[tx][ty + i*8];
}

// ============ 128x256 2-phase counted-vmcnt GEMM (T1+T2+T3'+T4+T5) ============
// C[M][N] = A[M][2048](bf16) @ Bt[N][2048](bf16)^T
// 8 waves (2m x 4n), per-wave 64x64, BK=64, LDS 96 KiB dbuf {A 16K, B 32K}.
// Stage: B0(kt+1)@p0, B1(kt+1)@p1, A(kt+2)@p1 (after p0-end consume-barrier).
// Steady-state wait vmcnt(4); tail 2 then 0.
// EPI=0: bias+RoPE+scatter to Q/K/V.  EPI=1: bias, f32 out.

#define SA_(kt, boff) do {                                                       \
    _Pragma("unroll") for (int L_ = 0; L_ < 2; ++L_)                             \
      GLD16(Ab + (size_t)(L_*64 + srow)*HID_ + (kt)*64 + su*8,                   \
            lds + (boff) + L_*8192 + t*16);                                      \
  } while (0)

#define SB_(kt, half, boff) do {                                                 \
    _Pragma("unroll") for (int L_ = 0; L_ < 2; ++L_)                             \
      GLD16(Bb + (size_t)((half)*128 + L_*64 + srow)*HID_ + (kt)*64 + su*8,      \
            lds + (boff) + 16384 + (half)*16384 + L_*8192 + t*16);               \
  } while (0)

#define RDA_(boff) do {                                                          \
    _Pragma("unroll") for (int q_ = 0; q_ < 4; ++q_)                             \
      _Pragma("unroll") for (int ks_ = 0; ks_ < 2; ++ks_)                        \
        af[q_][ks_] = *(const bf16x8*)(lds + (boff) + aBase + q_*2048            \
                                       + (((ks_*4+g) ^ key)*16));                \
  } while (0)

#define RDB_(nh, boff) do {                                                      \
    _Pragma("unroll") for (int n_ = 0; n_ < 2; ++n_)                             \
      _Pragma("unroll") for (int ks_ = 0; ks_ < 2; ++ks_)                        \
        bf[n_][ks_] = *(const bf16x8*)(lds + (boff) + bBase + ((nh)*2+n_)*2048   \
                                       + (((ks_*4+g) ^ key)*16));                \
  } while (0)

#define MM_(nh) do {                                                             \
    _Pragma("unroll") for (int q_ = 0; q_ < 4; ++q_)                             \
      _Pragma("unroll") for (int n_ = 0; n_ < 2; ++n_)                           \
        _Pragma("unroll") for (int ks_ = 0; ks_ < 2; ++ks_)                      \
          acc[q_][(nh)*2+n_] = __builtin_amdgcn_mfma_f32_16x16x32_bf16(          \
              af[q_][ks_], bf[n_][ks_], acc[q_][(nh)*2+n_], 0, 0, 0);            \
  } while (0)

template<int EPI, int BNX>
__global__ __launch_bounds__(512, 2) void k_g2(
    const __hip_bfloat16* __restrict__ A,
    const __hip_bfloat16* __restrict__ Bt,
    const float* __restrict__ bias,
    const int* __restrict__ pos_ids,
    __hip_bfloat16* __restrict__ Qb,
    __hip_bfloat16* __restrict__ Kb,
    __hip_bfloat16* __restrict__ Vb,
    float* __restrict__ outF) {
  extern __shared__ char lds[];   // 98304 B: 2 bufs x {A 16K, B 32K}
  const int nk = HID_ / 64;       // 32
  const int t = threadIdx.x, lane = t & 63, g = lane >> 4, c = lane & 15;
  const int w = t >> 6, wr = w >> 2, wc = w & 3;

  // XCD-aware decode: xcd owns BNX consecutive bn panels (L2-resident B)
  const int bid = blockIdx.x;
  const int xcd = bid & 7, idx = bid >> 3;
  const int bn = xcd * BNX + idx % BNX;
  const int bm = idx / BNX;

  const __hip_bfloat16* Ab = A  + (size_t)bm * 128 * HID_;
  const __hip_bfloat16* Bb = Bt + (size_t)bn * 256 * HID_;

  const int srow = t >> 3;                 // 0..63
  const int su   = (t & 7) ^ (srow & 7);   // pre-swizzled source unit
  const int aBase = (wr*64 + c) * 128;
  const int bBase = 16384 + (wc*64 + c) * 128;
  const int key = c & 7;

  f32x4 acc[4][4] = {};
  bf16x8 af[4][2], bf[2][2];

  // ---- prologue: T0 fully into buf0, A(1) into buf1 ----
  SA_(0, 0); SB_(0, 0, 0); SB_(0, 1, 0);
  SA_(1, 49152);
  asm volatile("s_waitcnt vmcnt(4)" ::: "memory");
  __builtin_amdgcn_s_barrier();

  for (int kt = 0; kt < nk; ++kt) {
    const int cb = (kt & 1) * 49152;
    const int nb = cb ^ 49152;

    // ---- p0: n-half 0 ----
    RDA_(cb); RDB_(0, cb);
    if (kt + 1 < nk) SB_(kt + 1, 0, nb);
    __builtin_amdgcn_s_barrier();
    __builtin_amdgcn_s_setprio(1);
    MM_(0);
    __builtin_amdgcn_s_setprio(0);
    if (kt + 1 < nk) asm volatile("s_waitcnt vmcnt(4)" ::: "memory");
    else             asm volatile("s_waitcnt vmcnt(0)" ::: "memory");
    __builtin_amdgcn_s_barrier();

    // ---- p1: n-half 1; stage B1(kt+1) and A(kt+2) (A region of cb consumed in p0) ----
    RDB_(1, cb);
    if (kt + 1 < nk) SB_(kt + 1, 1, nb);
    if (kt + 2 < nk) SA_(kt + 2, cb);
    __builtin_amdgcn_s_barrier();
    __builtin_amdgcn_s_setprio(1);
    MM_(1);
    __builtin_amdgcn_s_setprio(0);
    if (kt + 2 < nk)      asm volatile("s_waitcnt vmcnt(4)" ::: "memory");
    else if (kt + 1 < nk) asm volatile("s_waitcnt vmcnt(2)" ::: "memory");
    else                  asm volatile("s_waitcnt vmcnt(0)" ::: "memory");
    __builtin_amdgcn_s_barrier();
  }

  if (EPI == 0) {
    // ---- bias + RoPE + scatter to Q/K/V [bh][S][HD] bf16 ----
    #pragma unroll
    for (int mi = 0; mi < 4; ++mi) {
      const int m0 = bm*128 + wr*64 + mi*16 + g*4;
      #pragma unroll
      for (int ni = 0; ni < 4; ++ni) {
        const int n = bn*256 + wc*64 + ni*16 + c;
        const int h = n / 384;
        const int r = n - h*384;
        const int typ = r >> 7;       // 0=q 1=k 2=v (wave-uniform per frag)
        const int d = r & 127;
        if (typ == 2) {
          const float bv = bias[n];
          #pragma unroll
          for (int j = 0; j < 4; ++j) {
            int m = m0 + j; int b = m >> 11, s = m & 2047;
            Vb[((size_t)(b*H_ + h)*S_ + s)*HD_ + d] = __float2bfloat16(acc[mi][ni][j] + bv);
          }
        } else {
          __hip_bfloat16* op = typ ? Kb : Qb;
          if (d < 16) {               // rot low half; partner (d+16) is frag ni+1
            const float b0 = bias[n], b1 = bias[n + 16];
            const float invf = __expf(-(float)d * LN10000_OVER16);
            #pragma unroll
            for (int j = 0; j < 4; ++j) {
              int m = m0 + j; int b = m >> 11, s = m & 2047;
              float ang = (float)pos_ids[m] * invf;
              float sv, cv; sincosf(ang, &sv, &cv);
              float x1 = acc[mi][ni][j] + b0, x2 = acc[mi][ni + 1][j] + b1;
              size_t rb = ((size_t)(b*H_ + h)*S_ + s)*HD_;
              op[rb + d]      = __float2bfloat16(x1*cv - x2*sv);
              op[rb + d + 16] = __float2bfloat16(x2*cv + x1*sv);
            }
          } else if (d >= 32) {       // pass-through
            const float bv = bias[n];
            #pragma unroll
            for (int j = 0; j < 4; ++j) {
              int m = m0 + j; int b = m >> 11, s = m & 2047;
              op[((size_t)(b*H_ + h)*S_ + s)*HD_ + d] = __float2bfloat16(acc[mi][ni][j] + bv);
            }
          } // 16 <= d < 32: written by partner frag
        }
      }
    }
  } else {
    #pragma unroll
    for (int mi = 0; mi < 4; ++mi) {
      const int m0 = bm*128 + wr*64 + mi*16 + g*4;
      #pragma unroll
      for (int ni = 0; ni < 4; ++ni) {
        const int n = bn*256 + wc*64 + ni*16 + c;
        const float bv = bias[n];
        #pragma unroll
        for (int j = 0; j < 4; ++j) {
          int m = m0 + j;
          outF[(size_t)m*HID_ + n] = acc[mi][ni][j] + bv;
        }
      }
    }
  }
}

// ---------------- flash attention (unchanged) ----------------
__global__ __launch_bounds__(256) void k_attn(
    const __hip_bfloat16* __restrict__ Qb,
    const __hip_bfloat16* __restrict__ Kb,
    const __hip_bfloat16* __restrict__ VTb,
    __hip_bfloat16* __restrict__ Ob) {
  __shared__ char lds[49152];
  char* lK = lds;
  char* lV = lds + 16384;
  char* lPw = lds + 32768 + (threadIdx.x >> 6) * 4096;
  const int t = threadIdx.x, lane = t & 63, w = t >> 6, g = lane >> 4, c = lane & 15;
  const int bh = blockIdx.x, qt = 15 - blockIdx.y;
  const size_t base = (size_t)bh * S_ * HD_;
  const __hip_bfloat16* Qp = Qb + base;
  const __hip_bfloat16* Kp = Kb + base;
  const __hip_bfloat16* Vp = VTb + base;

  bf16x8 qf[2][4];
  #pragma unroll
  for (int mi = 0; mi < 2; ++mi) {
    int qrow = qt*128 + w*32 + mi*16 + c;
    #pragma unroll
    for (int kf = 0; kf < 4; ++kf)
      qf[mi][kf] = *(const bf16x8*)(Qp + (size_t)qrow*HD_ + kf*32 + g*8);
  }

  f32x4 oacc[2][8] = {};
  float mrun[2][4], lrun[2][4];
  #pragma unroll
  for (int mi = 0; mi < 2; ++mi)
    #pragma unroll
    for (int j = 0; j < 4; ++j) { mrun[mi][j] = -3.0e38f; lrun[mi][j] = 0.f; }

  const int nkt = qt*2 + 2;
  const float scale = 0.08838834764831845f;

  for (int kt = 0; kt < nkt; ++kt) {
    __syncthreads();
    #pragma unroll
    for (int i = 0; i < 4; ++i) {
      int idx = i*256 + t;
      int row = idx >> 4, u = idx & 15;
      GLD16(Kp + (size_t)(kt*64 + row)*HD_ + ((u ^ (row & 15)) * 8),
            lK + (i*256 + w*64)*16);
    }
    #pragma unroll
    for (int i = 0; i < 4; ++i) {
      int idx = i*256 + t;
      int dr = idx >> 3, u = idx & 7;
      GLD16(Vp + (size_t)dr*S_ + kt*64 + ((u ^ (dr & 7)) * 8),
            lV + (i*256 + w*64)*16);
    }
    __syncthreads();

    f32x4 sacc[2][4] = {};
    #pragma unroll
    for (int ni = 0; ni < 4; ++ni) {
      int krow = ni*16 + c;
      bf16x8 kfr[4];
      #pragma unroll
      for (int kf = 0; kf < 4; ++kf)
        kfr[kf] = *(const bf16x8*)(lK + krow*256 + (((kf*4 + g) ^ (krow & 15)) * 16));
      #pragma unroll
      for (int mi = 0; mi < 2; ++mi)
        #pragma unroll
        for (int kf = 0; kf < 4; ++kf)
          sacc[mi][ni] = __builtin_amdgcn_mfma_f32_16x16x32_bf16(qf[mi][kf], kfr[kf], sacc[mi][ni], 0, 0, 0);
    }

    #pragma unroll
    for (int mi = 0; mi < 2; ++mi) {
      #pragma unroll
      for (int j = 0; j < 4; ++j) {
        int row = qt*128 + w*32 + mi*16 + g*4 + j;
        float mx = -3.0e38f;
        #pragma unroll
        for (int ni = 0; ni < 4; ++ni) {
          int col = kt*64 + ni*16 + c;
          float sc = sacc[mi][ni][j] * scale;
          if (col > row) sc = -3.0e38f;
          sacc[mi][ni][j] = sc;
          mx = fmaxf(mx, sc);
        }
        mx = fmaxf(mx, __shfl_xor(mx, 1));
        mx = fmaxf(mx, __shfl_xor(mx, 2));
        mx = fmaxf(mx, __shfl_xor(mx, 4));
        mx = fmaxf(mx, __shfl_xor(mx, 8));
        float mnew = fmaxf(mrun[mi][j], mx);
        float fac = __expf(mrun[mi][j] - mnew);
        mrun[mi][j] = mnew;
        float ls = 0.f;
        int prow = mi*16 + g*4 + j;
        #pragma unroll
        for (int ni = 0; ni < 4; ++ni) {
          float pv = __expf(sacc[mi][ni][j] - mnew);
          ls += pv;
          int cu = (ni*2 + (c >> 3)) ^ (prow & 7);
          *(__hip_bfloat16*)(lPw + prow*128 + cu*16 + (c & 7)*2) = __float2bfloat16(pv);
        }
        ls += __shfl_xor(ls, 1);
        ls += __shfl_xor(ls, 2);
        ls += __shfl_xor(ls, 4);
        ls += __shfl_xor(ls, 8);
        lrun[mi][j] = lrun[mi][j]*fac + ls;
        #pragma unroll
        for (int nio = 0; nio < 8; ++nio) oacc[mi][nio][j] *= fac;
      }
    }
    __syncthreads();

    bf16x8 paf[2][2];
    #pragma unroll
    for (int mi = 0; mi < 2; ++mi)
      #pragma unroll
      for (int kc = 0; kc < 2; ++kc) {
        int prow = mi*16 + c;
        paf[mi][kc] = *(const bf16x8*)(lPw + prow*128 + (((kc*4 + g) ^ (prow & 7)) * 16));
      }
    #pragma unroll
    for (int nio = 0; nio < 8; ++nio) {
      int dr = nio*16 + c;
      bf16x8 v0 = *(const bf16x8*)(lV + dr*128 + (((g)     ^ (dr & 7)) * 16));
      bf16x8 v1 = *(const bf16x8*)(lV + dr*128 + (((4 + g) ^ (dr & 7)) * 16));
      #pragma unroll
      for (int mi = 0; mi < 2; ++mi) {
        oacc[mi][nio] = __builtin_amdgcn_mfma_f32_16x16x32_bf16(paf[mi][0], v0, oacc[mi][nio], 0, 0, 0);
        oacc[mi][nio] = __builtin_amdgcn_mfma_f32_16x16x32_bf16(paf[mi][1], v1, oacc[mi][nio], 0, 0, 0);
      }
    }
  }

  const int b = bh >> 4, h = bh & 15;
  #pragma unroll
  for (int mi = 0; mi < 2; ++mi)
    #pragma unroll
    for (int j = 0; j < 4; ++j) {
      int s = qt*128 + w*32 + mi*16 + g*4 + j;
      float inv = 1.0f / lrun[mi][j];
      size_t rb = ((size_t)(b*S_ + s))*HID_ + h*HD_;
      #pragma unroll
      for (int nio = 0; nio < 8; ++nio)
        Ob[rb + nio*16 + c] = __float2bfloat16(oacc[mi][nio][j] * inv);
    }
}

// ---------------- host launch ----------------
extern "C" void kernel_launch(void* const* d_in, const int* in_sizes, int n_in,
                              void* d_out, int out_size, void* d_ws, size_t ws_size,
                              hipStream_t stream) {
  const float* hs   = (const float*)d_in[0];
  const int*   pos  = (const int*)d_in[1];
  const float* Wqkv = (const float*)d_in[3];
  const float* bqkv = (const float*)d_in[4];
  const float* Wd   = (const float*)d_in[5];
  const float* bd   = (const float*)d_in[6];
  float* out = (float*)d_out;

  char* ws = (char*)d_ws;
  __hip_bfloat16* hsb = (__hip_bfloat16*)(ws);
  __hip_bfloat16* WqT = (__hip_bfloat16*)(ws + 16777216);
  __hip_bfloat16* WdT = (__hip_bfloat16*)(ws + 41943040);
  __hip_bfloat16* Qb  = (__hip_bfloat16*)(ws + 50331648);
  __hip_bfloat16* Kb  = (__hip_bfloat16*)(ws + 67108864);
  __hip_bfloat16* VTb = (__hip_bfloat16*)(ws + 83886080);
  __hip_bfloat16* Vb  = (__hip_bfloat16*)(ws + 100663296);

  hipFuncSetAttribute(reinterpret_cast<const void*>(&k_g2<0,3>),
                      hipFuncAttributeMaxDynamicSharedMemorySize, 98304);
  hipFuncSetAttribute(reinterpret_cast<const void*>(&k_g2<1,1>),
                      hipFuncAttributeMaxDynamicSharedMemorySize, 98304);

  k_cvt_bf16<<<8192, 256, 0, stream>>>(hs, hsb, (M_*HID_)/4);
  k_transpose_w<<<dim3(HID_/32, NQKV_/32), dim3(32, 8), 0, stream>>>(Wqkv, WqT, HID_, NQKV_);
  k_transpose_w<<<dim3(HID_/32, HID_/32), dim3(32, 8), 0, stream>>>(Wd, WdT, HID_, HID_);
  // QKV: grid 768 = 32 bm x 24 bn = 3 exact generations; xcd owns 3 bn panels
  k_g2<0,3><<<768, 512, 98304, stream>>>(hsb, WqT, bqkv, pos, Qb, Kb, Vb, nullptr);
  k_transpose_v<<<dim3(S_/32, HD_/32, B_*H_), dim3(32, 8), 0, stream>>>(Vb, VTb);
  k_attn<<<dim3(B_*H_, 16), 256, 0, stream>>>(Qb, Kb, VTb, Vb);
  // dense: grid 256 = 32 bm x 8 bn = 1 exact generation; xcd owns 1 bn panel
  k_g2<1,1><<<256, 512, 98304, stream>>>(Vb, WdT, bd, nullptr, nullptr, nullptr, nullptr, out);
}